// Round 1
// baseline (208.566 us; speedup 1.0000x reference)
//
#include <hip/hip_runtime.h>

#define BB 64
#define LCC 512
#define LQQ 64
#define DDD 256

typedef short bf16x8 __attribute__((ext_vector_type(8)));
typedef float f32x4 __attribute__((ext_vector_type(4)));

__device__ __forceinline__ unsigned short f2bf(float f) {
  union { float f; unsigned u; } v; v.f = f;
  unsigned u = v.u;
  return (unsigned short)((u + 0x7fffu + ((u >> 16) & 1u)) >> 16);
}
__device__ __forceinline__ float bf2f(unsigned u16) {
  union { unsigned u; float f; } v; v.u = u16 << 16;
  return v.f;
}

// ---------------------------------------------------------------------------
// Kernel 1: E = exp((cx*wi)@q^T + s_c + s_q + bias), rowsum_inv, E + E^T (bf16)
// grid 256 = B x 4 LC-tiles of 128; 256 threads (4 waves)
// ---------------------------------------------------------------------------
__global__ __launch_bounds__(256) void k1_scores(
    const float* __restrict__ cx, const float* __restrict__ qu,
    const float* __restrict__ W, const float* __restrict__ Wb,
    unsigned short* __restrict__ E, unsigned short* __restrict__ Et,
    float* __restrict__ rinv)
{
  __shared__ float w_lds[768];
  __shared__ unsigned short As[128 * 72];
  __shared__ unsigned short Bs[64 * 72];
  __shared__ float E_lds[128 * 65];   // also reused as "red" scratch in prologue
  __shared__ float sc_lds[128];
  __shared__ float sq_lds[64];
  float* red = E_lds;

  const int tid = threadIdx.x;
  const int b  = blockIdx.x >> 2;
  const int i0 = (blockIdx.x & 3) * 128;
  const int w = tid >> 6, lane = tid & 63, quad = lane >> 4, ln = lane & 15;

  for (int idx = tid; idx < 768; idx += 256) w_lds[idx] = W[idx];
  __syncthreads();

  // s_c partials: 2 threads per row
  {
    const int i = tid >> 1, h = tid & 1;
    const float4* src = (const float4*)(cx + ((size_t)(b * LCC + i0 + i)) * DDD + h * 128);
    const float* wc = w_lds + 256 + h * 128;
    float s = 0.f;
#pragma unroll
    for (int u = 0; u < 32; ++u) {
      float4 v = src[u];
      s += v.x * wc[u*4+0] + v.y * wc[u*4+1] + v.z * wc[u*4+2] + v.w * wc[u*4+3];
    }
    red[tid] = s;
  }
  __syncthreads();
  if (tid < 128) sc_lds[tid] = red[2*tid] + red[2*tid+1];
  __syncthreads();
  if (tid < 128) {
    const int j = tid >> 1, h = tid & 1;
    const float4* src = (const float4*)(qu + ((size_t)(b * LQQ + j)) * DDD + h * 128);
    const float* wq = w_lds + h * 128;
    float s = 0.f;
#pragma unroll
    for (int u = 0; u < 32; ++u) {
      float4 v = src[u];
      s += v.x * wq[u*4+0] + v.y * wq[u*4+1] + v.z * wq[u*4+2] + v.w * wq[u*4+3];
    }
    red[tid] = s;
  }
  __syncthreads();
  if (tid < 64) sq_lds[tid] = red[2*tid] + red[2*tid+1];

  f32x4 acc[2][4];
#pragma unroll
  for (int a = 0; a < 2; ++a)
#pragma unroll
    for (int c = 0; c < 4; ++c) acc[a][c] = (f32x4){0.f, 0.f, 0.f, 0.f};

  for (int kk = 0; kk < 4; ++kk) {
    __syncthreads();
    // stage A = cx * wi (bf16), tile 128 x 64, pitch 72
    {
      const int i = tid >> 1, h = tid & 1;
      const float4* src = (const float4*)(cx + ((size_t)(b * LCC + i0 + i)) * DDD + kk * 64 + h * 32);
      const float* wi = w_lds + 512 + kk * 64 + h * 32;
      unsigned short* dst = As + i * 72 + h * 32;
#pragma unroll
      for (int u = 0; u < 8; ++u) {
        float4 v = src[u];
        ushort4 o;
        o.x = f2bf(v.x * wi[u*4+0]);
        o.y = f2bf(v.y * wi[u*4+1]);
        o.z = f2bf(v.z * wi[u*4+2]);
        o.w = f2bf(v.w * wi[u*4+3]);
        *(ushort4*)(dst + u * 4) = o;
      }
    }
    // stage B = question rows (bf16), tile 64 x 64
    {
      const int j = tid >> 2, c = tid & 3;
      const float4* src = (const float4*)(qu + ((size_t)(b * LQQ + j)) * DDD + kk * 64 + c * 16);
      unsigned short* dst = Bs + j * 72 + c * 16;
#pragma unroll
      for (int u = 0; u < 4; ++u) {
        float4 v = src[u];
        ushort4 o = { f2bf(v.x), f2bf(v.y), f2bf(v.z), f2bf(v.w) };
        *(ushort4*)(dst + u * 4) = o;
      }
    }
    __syncthreads();
#pragma unroll
    for (int ks = 0; ks < 2; ++ks) {
      bf16x8 af[2];
#pragma unroll
      for (int tm = 0; tm < 2; ++tm)
        af[tm] = *(const bf16x8*)(As + (w * 32 + tm * 16 + ln) * 72 + ks * 32 + quad * 8);
#pragma unroll
      for (int tn = 0; tn < 4; ++tn) {
        bf16x8 bf = *(const bf16x8*)(Bs + (tn * 16 + ln) * 72 + ks * 32 + quad * 8);
#pragma unroll
        for (int tm = 0; tm < 2; ++tm)
          acc[tm][tn] = __builtin_amdgcn_mfma_f32_16x16x32_bf16(af[tm], bf, acc[tm][tn], 0, 0, 0);
      }
    }
  }

  const float bias = Wb[0];
  __syncthreads();
  // exp epilogue into E_lds (C/D layout: col=lane&15, row=quad*4+r)
#pragma unroll
  for (int tm = 0; tm < 2; ++tm)
#pragma unroll
    for (int tn = 0; tn < 4; ++tn)
#pragma unroll
      for (int r = 0; r < 4; ++r) {
        int il = w * 32 + tm * 16 + quad * 4 + r;
        int j  = tn * 16 + ln;
        float e = __expf(acc[tm][tn][r] + sc_lds[il] + sq_lds[j] + bias);
        E_lds[il * 65 + j] = e;
      }
  __syncthreads();
  if (tid < 128) {
    float s = 0.f;
#pragma unroll
    for (int j = 0; j < 64; ++j) s += E_lds[tid * 65 + j];
    rinv[b * LCC + i0 + tid] = 1.0f / s;
  }
  // write E natural (B, 512, 64) bf16
  {
    const int i = tid >> 1, h = tid & 1;
    unsigned short* dst = E + ((size_t)(b * LCC + i0 + i)) * 64 + h * 32;
    const float* srcr = E_lds + i * 65 + h * 32;
#pragma unroll
    for (int u = 0; u < 8; ++u) {
      ushort4 o = { f2bf(srcr[u*4+0]), f2bf(srcr[u*4+1]), f2bf(srcr[u*4+2]), f2bf(srcr[u*4+3]) };
      *(ushort4*)(dst + u * 4) = o;
    }
  }
  // write E^T (B, 64, 512) bf16
  {
    const int j = tid >> 2, c = tid & 3;
    unsigned short* dst = Et + ((size_t)(b * LQQ + j)) * LCC + i0 + c * 32;
#pragma unroll
    for (int u = 0; u < 8; ++u) {
      ushort4 o;
      o.x = f2bf(E_lds[(c*32 + u*4 + 0) * 65 + j]);
      o.y = f2bf(E_lds[(c*32 + u*4 + 1) * 65 + j]);
      o.z = f2bf(E_lds[(c*32 + u*4 + 2) * 65 + j]);
      o.w = f2bf(E_lds[(c*32 + u*4 + 3) * 65 + j]);
      *(ushort4*)(dst + u * 4) = o;
    }
  }
}

// ---------------------------------------------------------------------------
// Kernel 2: T = diag(1/colsum) * E^T @ contex -> T^T (bf16); also Q^T (bf16)
// grid 256 = B x 4 D-quarters of 64; 256 threads (4 waves)
// ---------------------------------------------------------------------------
__global__ __launch_bounds__(256) void k2_tmat(
    const float* __restrict__ cx, const float* __restrict__ qu,
    const unsigned short* __restrict__ Et,
    unsigned short* __restrict__ Qt, unsigned short* __restrict__ Tt)
{
  __shared__ unsigned short As2[64 * 72];
  __shared__ unsigned short Bs2[64 * 72];
  __shared__ float Tl[64 * 65];
  __shared__ float cs_lds[64];

  const int tid = threadIdx.x;
  const int b  = blockIdx.x >> 2;
  const int d0 = (blockIdx.x & 3) * 64;
  const int w = tid >> 6, lane = tid & 63, quad = lane >> 4, ln = lane & 15;

  // ---- transpose question chunk -> Qt ----
  {
    const int j = tid >> 2, c = tid & 3;
    const float4* src = (const float4*)(qu + ((size_t)(b * LQQ + j)) * DDD + d0 + c * 16);
#pragma unroll
    for (int u = 0; u < 4; ++u) {
      float4 v = src[u];
      Tl[j * 65 + c*16 + u*4 + 0] = v.x;
      Tl[j * 65 + c*16 + u*4 + 1] = v.y;
      Tl[j * 65 + c*16 + u*4 + 2] = v.z;
      Tl[j * 65 + c*16 + u*4 + 3] = v.w;
    }
  }
  __syncthreads();
  {
    const int d = tid & 63, cj = tid >> 6;
    unsigned short* dst = Qt + ((size_t)(b * DDD + d0 + d)) * 64 + cj * 16;
#pragma unroll
    for (int u = 0; u < 4; ++u) {
      ushort4 o;
      o.x = f2bf(Tl[(cj*16 + u*4 + 0) * 65 + d]);
      o.y = f2bf(Tl[(cj*16 + u*4 + 1) * 65 + d]);
      o.z = f2bf(Tl[(cj*16 + u*4 + 2) * 65 + d]);
      o.w = f2bf(Tl[(cj*16 + u*4 + 3) * 65 + d]);
      *(ushort4*)(dst + u * 4) = o;
    }
  }

  f32x4 acc[4];
#pragma unroll
  for (int c = 0; c < 4; ++c) acc[c] = (f32x4){0.f, 0.f, 0.f, 0.f};
  float csp = 0.f;

  const int sj = tid >> 2, sc = tid & 3;    // As2 staging coords (j, k-chunk)
  const int si = tid & 63, sc2 = tid >> 6;  // Bs2 staging coords (i, d-chunk)

  for (int kk = 0; kk < 8; ++kk) {
    __syncthreads();
    // stage As2 = Et[b][j][k0..k0+64], accumulate colsum partial in regs
    {
      const uint4* src = (const uint4*)(Et + ((size_t)(b * LQQ + sj)) * LCC + kk * 64 + sc * 16);
#pragma unroll
      for (int u = 0; u < 2; ++u) {
        uint4 raw = src[u];
        *(uint4*)(As2 + sj * 72 + sc * 16 + u * 8) = raw;
        csp += bf2f(raw.x & 0xffffu) + bf2f(raw.x >> 16)
             + bf2f(raw.y & 0xffffu) + bf2f(raw.y >> 16)
             + bf2f(raw.z & 0xffffu) + bf2f(raw.z >> 16)
             + bf2f(raw.w & 0xffffu) + bf2f(raw.w >> 16);
      }
    }
    // stage Bs2[d][i] = contex[k0+i][d0+d] transposed (bf16)
    {
      const float4* src = (const float4*)(cx + ((size_t)(b * LCC + kk * 64 + si)) * DDD + d0 + sc2 * 16);
#pragma unroll
      for (int u = 0; u < 4; ++u) {
        float4 v = src[u];
        Bs2[(sc2*16 + u*4 + 0) * 72 + si] = f2bf(v.x);
        Bs2[(sc2*16 + u*4 + 1) * 72 + si] = f2bf(v.y);
        Bs2[(sc2*16 + u*4 + 2) * 72 + si] = f2bf(v.z);
        Bs2[(sc2*16 + u*4 + 3) * 72 + si] = f2bf(v.w);
      }
    }
    __syncthreads();
#pragma unroll
    for (int ks = 0; ks < 2; ++ks) {
      bf16x8 af = *(const bf16x8*)(As2 + (w * 16 + ln) * 72 + ks * 32 + quad * 8);
#pragma unroll
      for (int tn = 0; tn < 4; ++tn) {
        bf16x8 bf = *(const bf16x8*)(Bs2 + (tn * 16 + ln) * 72 + ks * 32 + quad * 8);
        acc[tn] = __builtin_amdgcn_mfma_f32_16x16x32_bf16(af, bf, acc[tn], 0, 0, 0);
      }
    }
  }

  __syncthreads();
  Tl[tid] = csp;   // reuse Tl as reduction scratch (tid = j*4 + c)
  __syncthreads();
  if (tid < 64) {
    float s = Tl[4*tid] + Tl[4*tid+1] + Tl[4*tid+2] + Tl[4*tid+3];
    cs_lds[tid] = 1.0f / s;
  }
  __syncthreads();
  // scale by 1/colsum, park T in Tl
#pragma unroll
  for (int tn = 0; tn < 4; ++tn)
#pragma unroll
    for (int r = 0; r < 4; ++r) {
      int jl = w * 16 + quad * 4 + r;
      Tl[jl * 65 + tn * 16 + ln] = acc[tn][r] * cs_lds[jl];
    }
  __syncthreads();
  // write T^T (B, 256, 64) bf16
  {
    const int d = tid & 63, cj = tid >> 6;
    unsigned short* dst = Tt + ((size_t)(b * DDD + d0 + d)) * 64 + cj * 16;
#pragma unroll
    for (int u = 0; u < 4; ++u) {
      ushort4 o;
      o.x = f2bf(Tl[(cj*16 + u*4 + 0) * 65 + d]);
      o.y = f2bf(Tl[(cj*16 + u*4 + 1) * 65 + d]);
      o.z = f2bf(Tl[(cj*16 + u*4 + 2) * 65 + d]);
      o.w = f2bf(Tl[(cj*16 + u*4 + 3) * 65 + d]);
      *(ushort4*)(dst + u * 4) = o;
    }
  }
}

// ---------------------------------------------------------------------------
// Kernel 3: [A|Bm] = diag(1/rowsum) * E @ [q|T]; write all 4 output slabs
// grid 1024 = B x 8 LC-tiles of 64 x 2 halves; 256 threads (4 waves)
// ---------------------------------------------------------------------------
__global__ __launch_bounds__(256) void k3_out(
    const float* __restrict__ cx,
    const unsigned short* __restrict__ E,
    const unsigned short* __restrict__ Qt,
    const unsigned short* __restrict__ Tt,
    const float* __restrict__ rinv,
    float* __restrict__ out)
{
  __shared__ unsigned short As3[64 * 72];
  __shared__ unsigned short Bs3[256 * 72];
  __shared__ float ri_lds[64];

  const int tid = threadIdx.x;
  const int bid = blockIdx.x;
  const int b    = bid >> 4;
  const int it   = (bid >> 1) & 7;
  const int half = bid & 1;
  const int i0 = it * 64;
  const int w = tid >> 6, lane = tid & 63, quad = lane >> 4, ln = lane & 15;

  // stage As3 = E tile (64 x 64)
  {
    const int i = tid >> 2, c = tid & 3;
    const uint4* src = (const uint4*)(E + ((size_t)(b * LCC + i0 + i)) * 64 + c * 16);
#pragma unroll
    for (int u = 0; u < 2; ++u)
      *(uint4*)(As3 + i * 72 + c * 16 + u * 8) = src[u];
  }
  // stage Bs3 = Qt or Tt (256 x 64)
  {
    const unsigned short* Bsrc = half ? Tt : Qt;
    const int nb = tid & 63, c2 = tid >> 6;
#pragma unroll
    for (int rr = 0; rr < 4; ++rr) {
      int n = rr * 64 + nb;
      const uint4* src = (const uint4*)(Bsrc + ((size_t)(b * DDD + n)) * 64 + c2 * 16);
#pragma unroll
      for (int u = 0; u < 2; ++u)
        *(uint4*)(Bs3 + n * 72 + c2 * 16 + u * 8) = src[u];
    }
  }
  if (tid < 64) ri_lds[tid] = rinv[b * LCC + i0 + tid];
  __syncthreads();

  f32x4 acc[4][4];
#pragma unroll
  for (int a = 0; a < 4; ++a)
#pragma unroll
    for (int c = 0; c < 4; ++c) acc[a][c] = (f32x4){0.f, 0.f, 0.f, 0.f};

#pragma unroll
  for (int ks = 0; ks < 2; ++ks) {
    bf16x8 af[4], bf[4];
#pragma unroll
    for (int tm = 0; tm < 4; ++tm)
      af[tm] = *(const bf16x8*)(As3 + (tm * 16 + ln) * 72 + ks * 32 + quad * 8);
#pragma unroll
    for (int tn = 0; tn < 4; ++tn)
      bf[tn] = *(const bf16x8*)(Bs3 + (w * 64 + tn * 16 + ln) * 72 + ks * 32 + quad * 8);
#pragma unroll
    for (int tm = 0; tm < 4; ++tm)
#pragma unroll
      for (int tn = 0; tn < 4; ++tn)
        acc[tm][tn] = __builtin_amdgcn_mfma_f32_16x16x32_bf16(af[tm], bf[tn], acc[tm][tn], 0, 0, 0);
  }

  const float* cxb = cx + (size_t)b * LCC * DDD;
  float* ob = out + (size_t)b * LCC * 1024;
#pragma unroll
  for (int tm = 0; tm < 4; ++tm)
#pragma unroll
    for (int tn = 0; tn < 4; ++tn)
#pragma unroll
      for (int r = 0; r < 4; ++r) {
        int il = tm * 16 + quad * 4 + r;
        int i = i0 + il;
        int n = w * 64 + tn * 16 + ln;
        float v = acc[tm][tn][r] * ri_lds[il];
        float c = cxb[(size_t)i * DDD + n];
        if (half == 0) {
          ob[(size_t)i * 1024 + 256 + n] = v;       // A
          ob[(size_t)i * 1024 + 512 + n] = c * v;   // contex * A
        } else {
          ob[(size_t)i * 1024 + n]       = c;       // contex copy
          ob[(size_t)i * 1024 + 768 + n] = c * v;   // contex * Bm
        }
      }
}

extern "C" void kernel_launch(void* const* d_in, const int* in_sizes, int n_in,
                              void* d_out, int out_size, void* d_ws, size_t ws_size,
                              hipStream_t stream) {
  const float* cx = (const float*)d_in[0];
  const float* qu = (const float*)d_in[1];
  const float* W  = (const float*)d_in[2];
  const float* Wb = (const float*)d_in[3];
  float* out = (float*)d_out;

  char* wsb = (char*)d_ws;
  unsigned short* E   = (unsigned short*)(wsb);                       // 4 MiB
  unsigned short* Et  = (unsigned short*)(wsb + (4ull << 20));        // 4 MiB
  unsigned short* Qt  = (unsigned short*)(wsb + (8ull << 20));        // 2 MiB
  unsigned short* Tt  = (unsigned short*)(wsb + (10ull << 20));       // 2 MiB
  float*          ri  = (float*)(wsb + (12ull << 20));                // 128 KiB

  k1_scores<<<dim3(256), dim3(256), 0, stream>>>(cx, qu, W, Wb, E, Et, ri);
  k2_tmat  <<<dim3(256), dim3(256), 0, stream>>>(cx, qu, Et, Qt, Tt);
  k3_out   <<<dim3(1024), dim3(256), 0, stream>>>(cx, E, Qt, Tt, ri, out);
}

// Round 2
// 199.588 us; speedup vs baseline: 1.0450x; 1.0450x over previous
//
#include <hip/hip_runtime.h>

#define BB 64
#define LCC 512
#define LQQ 64
#define DDD 256

typedef short bf16x8 __attribute__((ext_vector_type(8)));
typedef float f32x4 __attribute__((ext_vector_type(4)));

__device__ __forceinline__ unsigned short f2bf(float f) {
  union { float f; unsigned u; } v; v.f = f;
  unsigned u = v.u;
  return (unsigned short)((u + 0x7fffu + ((u >> 16) & 1u)) >> 16);
}
__device__ __forceinline__ float bf2f(unsigned u16) {
  union { unsigned u; float f; } v; v.u = u16 << 16;
  return v.f;
}

// ---------------------------------------------------------------------------
// Kernel 1: E = exp((cx*wi)@q^T + s_c + s_q + bias), rowsum_inv, E + E^T (bf16)
// s_c / s_q folded into the staging pass (single read of cx / qu).
// grid 256 = B x 4 LC-tiles of 128; 256 threads (4 waves)
// ---------------------------------------------------------------------------
__global__ __launch_bounds__(256) void k1_scores(
    const float* __restrict__ cx, const float* __restrict__ qu,
    const float* __restrict__ W, const float* __restrict__ Wb,
    unsigned short* __restrict__ E, unsigned short* __restrict__ Et,
    float* __restrict__ rinv)
{
  __shared__ float w_lds[768];           // wq|wc|wi, reused as reduction scratch
  __shared__ unsigned short As[128 * 72];
  __shared__ unsigned short Bs[64 * 72];
  __shared__ float E_lds[128 * 65];
  __shared__ float sc_lds[128];
  __shared__ float sq_lds[64];

  const int tid = threadIdx.x;
  const int b  = blockIdx.x >> 2;
  const int i0 = (blockIdx.x & 3) * 128;
  const int w = tid >> 6, lane = tid & 63, quad = lane >> 4, ln = lane & 15;

  for (int idx = tid; idx < 768; idx += 256) w_lds[idx] = W[idx];

  f32x4 acc[2][4];
#pragma unroll
  for (int a = 0; a < 2; ++a)
#pragma unroll
    for (int c = 0; c < 4; ++c) acc[a][c] = (f32x4){0.f, 0.f, 0.f, 0.f};

  float scp = 0.f;   // s_c partial (this thread's half-row slice of cx . wc)
  float sqp = 0.f;   // s_q partial (this thread's quarter-row slice of qu . wq)
  const int ai = tid >> 1, ah = tid & 1;      // A staging coords
  const int bj = tid >> 2, bc = tid & 3;      // B staging coords

  for (int kk = 0; kk < 4; ++kk) {
    __syncthreads();
    // stage A = cx * wi (bf16), tile 128 x 64, pitch 72; accumulate s_c partial
    {
      const float4* src = (const float4*)(cx + ((size_t)(b * LCC + i0 + ai)) * DDD + kk * 64 + ah * 32);
      const float* wi = w_lds + 512 + kk * 64 + ah * 32;
      const float* wc = w_lds + 256 + kk * 64 + ah * 32;
      unsigned short* dst = As + ai * 72 + ah * 32;
#pragma unroll
      for (int u = 0; u < 8; ++u) {
        float4 v = src[u];
        scp += v.x * wc[u*4+0] + v.y * wc[u*4+1] + v.z * wc[u*4+2] + v.w * wc[u*4+3];
        ushort4 o;
        o.x = f2bf(v.x * wi[u*4+0]);
        o.y = f2bf(v.y * wi[u*4+1]);
        o.z = f2bf(v.z * wi[u*4+2]);
        o.w = f2bf(v.w * wi[u*4+3]);
        *(ushort4*)(dst + u * 4) = o;
      }
    }
    // stage B = question rows (bf16), tile 64 x 64; accumulate s_q partial
    {
      const float4* src = (const float4*)(qu + ((size_t)(b * LQQ + bj)) * DDD + kk * 64 + bc * 16);
      const float* wq = w_lds + kk * 64 + bc * 16;
      unsigned short* dst = Bs + bj * 72 + bc * 16;
#pragma unroll
      for (int u = 0; u < 4; ++u) {
        float4 v = src[u];
        sqp += v.x * wq[u*4+0] + v.y * wq[u*4+1] + v.z * wq[u*4+2] + v.w * wq[u*4+3];
        ushort4 o = { f2bf(v.x), f2bf(v.y), f2bf(v.z), f2bf(v.w) };
        *(ushort4*)(dst + u * 4) = o;
      }
    }
    __syncthreads();
#pragma unroll
    for (int ks = 0; ks < 2; ++ks) {
      bf16x8 af[2];
#pragma unroll
      for (int tm = 0; tm < 2; ++tm)
        af[tm] = *(const bf16x8*)(As + (w * 32 + tm * 16 + ln) * 72 + ks * 32 + quad * 8);
#pragma unroll
      for (int tn = 0; tn < 4; ++tn) {
        bf16x8 bf = *(const bf16x8*)(Bs + (tn * 16 + ln) * 72 + ks * 32 + quad * 8);
#pragma unroll
        for (int tm = 0; tm < 2; ++tm)
          acc[tm][tn] = __builtin_amdgcn_mfma_f32_16x16x32_bf16(af[tm], bf, acc[tm][tn], 0, 0, 0);
      }
    }
  }

  // reduce s_c (2 partials/row) and s_q (4 partials/row) through w_lds scratch
  __syncthreads();
  w_lds[tid] = scp;
  w_lds[256 + tid] = sqp;
  __syncthreads();
  if (tid < 128) sc_lds[tid] = w_lds[2*tid] + w_lds[2*tid+1];
  if (tid < 64)
    sq_lds[tid] = w_lds[256 + 4*tid] + w_lds[256 + 4*tid+1]
                + w_lds[256 + 4*tid+2] + w_lds[256 + 4*tid+3];
  const float bias = Wb[0];
  __syncthreads();

  // exp epilogue into E_lds (C/D layout: col=lane&15, row=quad*4+r)
#pragma unroll
  for (int tm = 0; tm < 2; ++tm)
#pragma unroll
    for (int tn = 0; tn < 4; ++tn)
#pragma unroll
      for (int r = 0; r < 4; ++r) {
        int il = w * 32 + tm * 16 + quad * 4 + r;
        int j  = tn * 16 + ln;
        float e = __expf(acc[tm][tn][r] + sc_lds[il] + sq_lds[j] + bias);
        E_lds[il * 65 + j] = e;
      }
  __syncthreads();
  // rowsum with all 256 threads (each sums a half-row)
  {
    float s = 0.f;
#pragma unroll
    for (int j = 0; j < 32; ++j) s += E_lds[ai * 65 + ah * 32 + j];
    w_lds[tid] = s;
  }
  __syncthreads();
  if (tid < 128) rinv[b * LCC + i0 + tid] = 1.0f / (w_lds[2*tid] + w_lds[2*tid+1]);

  // write E natural (B, 512, 64) bf16
  {
    unsigned short* dst = E + ((size_t)(b * LCC + i0 + ai)) * 64 + ah * 32;
    const float* srcr = E_lds + ai * 65 + ah * 32;
#pragma unroll
    for (int u = 0; u < 8; ++u) {
      ushort4 o = { f2bf(srcr[u*4+0]), f2bf(srcr[u*4+1]), f2bf(srcr[u*4+2]), f2bf(srcr[u*4+3]) };
      *(ushort4*)(dst + u * 4) = o;
    }
  }
  // write E^T (B, 64, 512) bf16
  {
    unsigned short* dst = Et + ((size_t)(b * LQQ + bj)) * LCC + i0 + bc * 32;
#pragma unroll
    for (int u = 0; u < 8; ++u) {
      ushort4 o;
      o.x = f2bf(E_lds[(bc*32 + u*4 + 0) * 65 + bj]);
      o.y = f2bf(E_lds[(bc*32 + u*4 + 1) * 65 + bj]);
      o.z = f2bf(E_lds[(bc*32 + u*4 + 2) * 65 + bj]);
      o.w = f2bf(E_lds[(bc*32 + u*4 + 3) * 65 + bj]);
      *(ushort4*)(dst + u * 4) = o;
    }
  }
}

// ---------------------------------------------------------------------------
// Kernel 2: T = diag(1/colsum) * E^T @ contex -> T^T (bf16); also Q^T (bf16)
// grid 256 = B x 4 D-quarters of 64; 256 threads (4 waves)
// ---------------------------------------------------------------------------
__global__ __launch_bounds__(256) void k2_tmat(
    const float* __restrict__ cx, const float* __restrict__ qu,
    const unsigned short* __restrict__ Et,
    unsigned short* __restrict__ Qt, unsigned short* __restrict__ Tt)
{
  __shared__ unsigned short As2[64 * 72];
  __shared__ unsigned short Bs2[64 * 72];
  __shared__ float Tl[64 * 65];
  __shared__ float cs_lds[64];

  const int tid = threadIdx.x;
  const int b  = blockIdx.x >> 2;
  const int d0 = (blockIdx.x & 3) * 64;
  const int w = tid >> 6, lane = tid & 63, quad = lane >> 4, ln = lane & 15;

  // ---- transpose question chunk -> Qt ----
  {
    const int j = tid >> 2, c = tid & 3;
    const float4* src = (const float4*)(qu + ((size_t)(b * LQQ + j)) * DDD + d0 + c * 16);
#pragma unroll
    for (int u = 0; u < 4; ++u) {
      float4 v = src[u];
      Tl[j * 65 + c*16 + u*4 + 0] = v.x;
      Tl[j * 65 + c*16 + u*4 + 1] = v.y;
      Tl[j * 65 + c*16 + u*4 + 2] = v.z;
      Tl[j * 65 + c*16 + u*4 + 3] = v.w;
    }
  }
  __syncthreads();
  {
    const int d = tid & 63, cj = tid >> 6;
    unsigned short* dst = Qt + ((size_t)(b * DDD + d0 + d)) * 64 + cj * 16;
#pragma unroll
    for (int u = 0; u < 4; ++u) {
      ushort4 o;
      o.x = f2bf(Tl[(cj*16 + u*4 + 0) * 65 + d]);
      o.y = f2bf(Tl[(cj*16 + u*4 + 1) * 65 + d]);
      o.z = f2bf(Tl[(cj*16 + u*4 + 2) * 65 + d]);
      o.w = f2bf(Tl[(cj*16 + u*4 + 3) * 65 + d]);
      *(ushort4*)(dst + u * 4) = o;
    }
  }

  f32x4 acc[4];
#pragma unroll
  for (int c = 0; c < 4; ++c) acc[c] = (f32x4){0.f, 0.f, 0.f, 0.f};
  float csp = 0.f;

  const int sj = tid >> 2, sc = tid & 3;    // As2 staging coords (j, k-chunk)
  const int si = tid & 63, sc2 = tid >> 6;  // Bs2 staging coords (i, d-chunk)

  for (int kk = 0; kk < 8; ++kk) {
    __syncthreads();
    // stage As2 = Et[b][j][k0..k0+64], accumulate colsum partial in regs
    {
      const uint4* src = (const uint4*)(Et + ((size_t)(b * LQQ + sj)) * LCC + kk * 64 + sc * 16);
#pragma unroll
      for (int u = 0; u < 2; ++u) {
        uint4 raw = src[u];
        *(uint4*)(As2 + sj * 72 + sc * 16 + u * 8) = raw;
        csp += bf2f(raw.x & 0xffffu) + bf2f(raw.x >> 16)
             + bf2f(raw.y & 0xffffu) + bf2f(raw.y >> 16)
             + bf2f(raw.z & 0xffffu) + bf2f(raw.z >> 16)
             + bf2f(raw.w & 0xffffu) + bf2f(raw.w >> 16);
      }
    }
    // stage Bs2[d][i] = contex[k0+i][d0+d] transposed (bf16)
    {
      const float4* src = (const float4*)(cx + ((size_t)(b * LCC + kk * 64 + si)) * DDD + d0 + sc2 * 16);
#pragma unroll
      for (int u = 0; u < 4; ++u) {
        float4 v = src[u];
        Bs2[(sc2*16 + u*4 + 0) * 72 + si] = f2bf(v.x);
        Bs2[(sc2*16 + u*4 + 1) * 72 + si] = f2bf(v.y);
        Bs2[(sc2*16 + u*4 + 2) * 72 + si] = f2bf(v.z);
        Bs2[(sc2*16 + u*4 + 3) * 72 + si] = f2bf(v.w);
      }
    }
    __syncthreads();
#pragma unroll
    for (int ks = 0; ks < 2; ++ks) {
      bf16x8 af = *(const bf16x8*)(As2 + (w * 16 + ln) * 72 + ks * 32 + quad * 8);
#pragma unroll
      for (int tn = 0; tn < 4; ++tn) {
        bf16x8 bf = *(const bf16x8*)(Bs2 + (tn * 16 + ln) * 72 + ks * 32 + quad * 8);
        acc[tn] = __builtin_amdgcn_mfma_f32_16x16x32_bf16(af, bf, acc[tn], 0, 0, 0);
      }
    }
  }

  __syncthreads();
  Tl[tid] = csp;   // reuse Tl as reduction scratch (tid = j*4 + c)
  __syncthreads();
  if (tid < 64) {
    float s = Tl[4*tid] + Tl[4*tid+1] + Tl[4*tid+2] + Tl[4*tid+3];
    cs_lds[tid] = 1.0f / s;
  }
  __syncthreads();
  // scale by 1/colsum, park T in Tl
#pragma unroll
  for (int tn = 0; tn < 4; ++tn)
#pragma unroll
    for (int r = 0; r < 4; ++r) {
      int jl = w * 16 + quad * 4 + r;
      Tl[jl * 65 + tn * 16 + ln] = acc[tn][r] * cs_lds[jl];
    }
  __syncthreads();
  // write T^T (B, 256, 64) bf16
  {
    const int d = tid & 63, cj = tid >> 6;
    unsigned short* dst = Tt + ((size_t)(b * DDD + d0 + d)) * 64 + cj * 16;
#pragma unroll
    for (int u = 0; u < 4; ++u) {
      ushort4 o;
      o.x = f2bf(Tl[(cj*16 + u*4 + 0) * 65 + d]);
      o.y = f2bf(Tl[(cj*16 + u*4 + 1) * 65 + d]);
      o.z = f2bf(Tl[(cj*16 + u*4 + 2) * 65 + d]);
      o.w = f2bf(Tl[(cj*16 + u*4 + 3) * 65 + d]);
      *(ushort4*)(dst + u * 4) = o;
    }
  }
}

// ---------------------------------------------------------------------------
// Kernel 3: [A|Bm] = diag(1/rowsum) * E @ [q|T]; vectorized epilogue via
// LDS transpose (16-row chunks, pitch 260 floats -> max 2-way bank alias).
// grid 1024 = B x 8 LC-tiles of 64 x 2 halves; 256 threads (4 waves)
// ---------------------------------------------------------------------------
__global__ __launch_bounds__(256) void k3_out(
    const float* __restrict__ cx,
    const unsigned short* __restrict__ E,
    const unsigned short* __restrict__ Qt,
    const unsigned short* __restrict__ Tt,
    const float* __restrict__ rinv,
    float* __restrict__ out)
{
  __shared__ unsigned short As3[64 * 72];
  __shared__ char BsTr[256 * 72 * 2];   // union: Bs3 (bf16 MFMA B-tile) / Tr (fp32 transpose buf)
  __shared__ float ri_lds[64];
  unsigned short* Bs3 = (unsigned short*)BsTr;
  float* Tr = (float*)BsTr;             // 16 rows x 260 floats (16640 B <= 36864 B)

  const int tid = threadIdx.x;
  const int bid = blockIdx.x;
  const int b    = bid >> 4;
  const int it   = (bid >> 1) & 7;
  const int half = bid & 1;
  const int i0 = it * 64;
  const int w = tid >> 6, lane = tid & 63, quad = lane >> 4, ln = lane & 15;

  // stage As3 = E tile (64 x 64)
  {
    const int i = tid >> 2, c = tid & 3;
    const uint4* src = (const uint4*)(E + ((size_t)(b * LCC + i0 + i)) * 64 + c * 16);
#pragma unroll
    for (int u = 0; u < 2; ++u)
      *(uint4*)(As3 + i * 72 + c * 16 + u * 8) = src[u];
  }
  // stage Bs3 = Qt or Tt (256 x 64)
  {
    const unsigned short* Bsrc = half ? Tt : Qt;
    const int nb = tid & 63, c2 = tid >> 6;
#pragma unroll
    for (int rr = 0; rr < 4; ++rr) {
      int n = rr * 64 + nb;
      const uint4* src = (const uint4*)(Bsrc + ((size_t)(b * DDD + n)) * 64 + c2 * 16);
#pragma unroll
      for (int u = 0; u < 2; ++u)
        *(uint4*)(Bs3 + n * 72 + c2 * 16 + u * 8) = src[u];
    }
  }
  if (tid < 64) ri_lds[tid] = rinv[b * LCC + i0 + tid];
  __syncthreads();

  f32x4 acc[4][4];
#pragma unroll
  for (int a = 0; a < 4; ++a)
#pragma unroll
    for (int c = 0; c < 4; ++c) acc[a][c] = (f32x4){0.f, 0.f, 0.f, 0.f};

#pragma unroll
  for (int ks = 0; ks < 2; ++ks) {
    bf16x8 af[4], bf[4];
#pragma unroll
    for (int tm = 0; tm < 4; ++tm)
      af[tm] = *(const bf16x8*)(As3 + (tm * 16 + ln) * 72 + ks * 32 + quad * 8);
#pragma unroll
    for (int tn = 0; tn < 4; ++tn)
      bf[tn] = *(const bf16x8*)(Bs3 + (w * 64 + tn * 16 + ln) * 72 + ks * 32 + quad * 8);
#pragma unroll
    for (int tm = 0; tm < 4; ++tm)
#pragma unroll
      for (int tn = 0; tn < 4; ++tn)
        acc[tm][tn] = __builtin_amdgcn_mfma_f32_16x16x32_bf16(af[tm], bf[tn], acc[tm][tn], 0, 0, 0);
  }

  const float* cxb = cx + (size_t)b * LCC * DDD;
  float* ob = out + (size_t)b * LCC * 1024;
  const int row = tid >> 4;   // 0..15: row within the 16-row chunk
  const int fq  = tid & 15;   // float4-group

#pragma unroll
  for (int tm = 0; tm < 4; ++tm) {
    __syncthreads();   // Bs3 MFMA reads done (tm=0) / previous chunk reads done
    // park 16 rows x 256 cols, rowsum-scaled, C/D-layout -> row-major
#pragma unroll
    for (int tn = 0; tn < 4; ++tn)
#pragma unroll
      for (int r = 0; r < 4; ++r) {
        int rloc = quad * 4 + r;
        Tr[rloc * 260 + w * 64 + tn * 16 + ln] = acc[tm][tn][r] * ri_lds[tm * 16 + rloc];
      }
    __syncthreads();
    const int i = i0 + tm * 16 + row;
#pragma unroll
    for (int u = 0; u < 4; ++u) {
      int c0 = (fq + u * 16) * 4;
      float4 v = *(const float4*)(Tr + row * 260 + c0);
      float4 c = *(const float4*)(cxb + (size_t)i * DDD + c0);
      float4 cv = { c.x * v.x, c.y * v.y, c.z * v.z, c.w * v.w };
      if (half == 0) {
        *(float4*)(ob + (size_t)i * 1024 + 256 + c0) = v;    // A
        *(float4*)(ob + (size_t)i * 1024 + 512 + c0) = cv;   // contex * A
      } else {
        *(float4*)(ob + (size_t)i * 1024 + c0)       = c;    // contex copy
        *(float4*)(ob + (size_t)i * 1024 + 768 + c0) = cv;   // contex * Bm
      }
    }
  }
}

extern "C" void kernel_launch(void* const* d_in, const int* in_sizes, int n_in,
                              void* d_out, int out_size, void* d_ws, size_t ws_size,
                              hipStream_t stream) {
  const float* cx = (const float*)d_in[0];
  const float* qu = (const float*)d_in[1];
  const float* W  = (const float*)d_in[2];
  const float* Wb = (const float*)d_in[3];
  float* out = (float*)d_out;

  char* wsb = (char*)d_ws;
  unsigned short* E   = (unsigned short*)(wsb);                       // 4 MiB
  unsigned short* Et  = (unsigned short*)(wsb + (4ull << 20));        // 4 MiB
  unsigned short* Qt  = (unsigned short*)(wsb + (8ull << 20));        // 2 MiB
  unsigned short* Tt  = (unsigned short*)(wsb + (10ull << 20));       // 2 MiB
  float*          ri  = (float*)(wsb + (12ull << 20));                // 128 KiB

  k1_scores<<<dim3(256), dim3(256), 0, stream>>>(cx, qu, W, Wb, E, Et, ri);
  k2_tmat  <<<dim3(256), dim3(256), 0, stream>>>(cx, qu, Et, Qt, Tt);
  k3_out   <<<dim3(1024), dim3(256), 0, stream>>>(cx, E, Qt, Tt, ri, out);
}

// Round 3
// 198.858 us; speedup vs baseline: 1.0488x; 1.0037x over previous
//
#include <hip/hip_runtime.h>

#define BB 64
#define LCC 512
#define LQQ 64
#define DDD 256

typedef short bf16x8 __attribute__((ext_vector_type(8)));
typedef float f32x4 __attribute__((ext_vector_type(4)));

static __device__ __forceinline__ unsigned short f2bf(float f) {
  union { float f; unsigned u; } v; v.f = f;
  unsigned u = v.u;
  return (unsigned short)((u + 0x7fffu + ((u >> 16) & 1u)) >> 16);
}
static __device__ __forceinline__ float bf2f(unsigned u16) {
  union { unsigned u; float f; } v; v.u = (u16 & 0xffffu) << 16;
  return v.f;
}

// ---------------------------------------------------------------------------
// Kernel 1: E = exp((cx*wi)@qu^T + s_c + s_q + bias), rinv, E + E^T (bf16)
// Direct-global A fragments (cx rows are k-contiguous); qu staged once K=256.
// grid 512 = B x 8 LC-tiles of 64; 256 threads (4 waves). LDS ~54KB -> 2/CU.
// ---------------------------------------------------------------------------
__global__ __launch_bounds__(256) void k1_scores(
    const float* __restrict__ cx, const float* __restrict__ qu,
    const float* __restrict__ W, const float* __restrict__ Wb,
    unsigned short* __restrict__ E, unsigned short* __restrict__ Et,
    float* __restrict__ rinv)
{
  __shared__ float w_lds[768];                 // wq | wc | wi
  __shared__ unsigned short Bs[64 * 264];      // qu tile bf16, full K, +8 pad
  __shared__ float E_lds[64 * 65];
  __shared__ float red[256];
  __shared__ float sc_lds[64];
  __shared__ float sq_lds[64];

  const int tid = threadIdx.x;
  const int b  = blockIdx.x >> 3;
  const int i0 = (blockIdx.x & 7) * 64;
  const int w = tid >> 6, lane = tid & 63, quad = lane >> 4, ln = lane & 15;

  for (int idx = tid; idx < 768; idx += 256) w_lds[idx] = W[idx];
  __syncthreads();

  // stage Bs = qu (bf16, 64 x 256), fold s_q partials
  {
    const int bj = tid >> 2, bc = tid & 3;
    const float4* src = (const float4*)(qu + ((size_t)(b * LQQ + bj)) * DDD + bc * 64);
    const float* wq = w_lds + bc * 64;
    unsigned short* dst = Bs + bj * 264 + bc * 64;
    float sqp = 0.f;
#pragma unroll
    for (int u = 0; u < 16; ++u) {
      float4 v = src[u];
      sqp += v.x * wq[u*4+0] + v.y * wq[u*4+1] + v.z * wq[u*4+2] + v.w * wq[u*4+3];
      ushort4 o = { f2bf(v.x), f2bf(v.y), f2bf(v.z), f2bf(v.w) };
      *(ushort4*)(dst + u * 4) = o;
    }
    red[tid] = sqp;
  }
  __syncthreads();
  if (tid < 64) sq_lds[tid] = red[4*tid] + red[4*tid+1] + red[4*tid+2] + red[4*tid+3];

  f32x4 acc[4];
#pragma unroll
  for (int c = 0; c < 4; ++c) acc[c] = (f32x4){0.f, 0.f, 0.f, 0.f};

  // K loop: no barriers. A fragment = cx row (w*16+ln), k-slice quad*8.
  float scp = 0.f;
  const float* cxrow = cx + ((size_t)(b * LCC + i0 + w * 16 + ln)) * DDD;
#pragma unroll
  for (int kk = 0; kk < 4; ++kk)
#pragma unroll
    for (int ks = 0; ks < 2; ++ks) {
      const int k0 = kk * 64 + ks * 32 + quad * 8;
      float4 c0 = *(const float4*)(cxrow + k0);
      float4 c1 = *(const float4*)(cxrow + k0 + 4);
      const float* wcp = w_lds + 256 + k0;
      const float* wip = w_lds + 512 + k0;
      scp += c0.x*wcp[0] + c0.y*wcp[1] + c0.z*wcp[2] + c0.w*wcp[3]
           + c1.x*wcp[4] + c1.y*wcp[5] + c1.z*wcp[6] + c1.w*wcp[7];
      bf16x8 af;
      af[0] = (short)f2bf(c0.x * wip[0]);
      af[1] = (short)f2bf(c0.y * wip[1]);
      af[2] = (short)f2bf(c0.z * wip[2]);
      af[3] = (short)f2bf(c0.w * wip[3]);
      af[4] = (short)f2bf(c1.x * wip[4]);
      af[5] = (short)f2bf(c1.y * wip[5]);
      af[6] = (short)f2bf(c1.z * wip[6]);
      af[7] = (short)f2bf(c1.w * wip[7]);
#pragma unroll
      for (int tn = 0; tn < 4; ++tn) {
        bf16x8 bf = *(const bf16x8*)(Bs + (tn * 16 + ln) * 264 + k0);
        acc[tn] = __builtin_amdgcn_mfma_f32_16x16x32_bf16(af, bf, acc[tn], 0, 0, 0);
      }
    }

  // reduce s_c (4 quad-partials per row), add bias
  __syncthreads();
  red[(w * 16 + ln) * 4 + quad] = scp;
  __syncthreads();
  if (tid < 64)
    sc_lds[tid] = red[4*tid] + red[4*tid+1] + red[4*tid+2] + red[4*tid+3] + Wb[0];
  __syncthreads();

  // exp epilogue into E_lds (C/D layout: col=lane&15, row=quad*4+r)
#pragma unroll
  for (int tn = 0; tn < 4; ++tn)
#pragma unroll
    for (int r = 0; r < 4; ++r) {
      int il = w * 16 + quad * 4 + r;
      int j  = tn * 16 + ln;
      E_lds[il * 65 + j] = __expf(acc[tn][r] + sc_lds[il] + sq_lds[j]);
    }
  __syncthreads();
  // rowsum (4 threads/row)
  {
    const int i = tid >> 2, c = tid & 3;
    float s = 0.f;
#pragma unroll
    for (int j = 0; j < 16; ++j) s += E_lds[i * 65 + c * 16 + j];
    red[tid] = s;
  }
  __syncthreads();
  if (tid < 64)
    rinv[b * LCC + i0 + tid] = 1.0f / (red[4*tid] + red[4*tid+1] + red[4*tid+2] + red[4*tid+3]);

  // write E natural (B, 512, 64) bf16
  {
    const int i = tid >> 2, c = tid & 3;
    unsigned short* dst = E + ((size_t)(b * LCC + i0 + i)) * 64 + c * 16;
    const float* srcr = E_lds + i * 65 + c * 16;
#pragma unroll
    for (int u = 0; u < 4; ++u) {
      ushort4 o = { f2bf(srcr[u*4+0]), f2bf(srcr[u*4+1]), f2bf(srcr[u*4+2]), f2bf(srcr[u*4+3]) };
      *(ushort4*)(dst + u * 4) = o;
    }
  }
  // write E^T (B, 64, 512) bf16
  {
    const int j = tid >> 2, c = tid & 3;
    unsigned short* dst = Et + ((size_t)(b * LQQ + j)) * LCC + i0 + c * 16;
#pragma unroll
    for (int u = 0; u < 4; ++u) {
      ushort4 o;
      o.x = f2bf(E_lds[(c*16 + u*4 + 0) * 65 + j]);
      o.y = f2bf(E_lds[(c*16 + u*4 + 1) * 65 + j]);
      o.z = f2bf(E_lds[(c*16 + u*4 + 2) * 65 + j]);
      o.w = f2bf(E_lds[(c*16 + u*4 + 3) * 65 + j]);
      *(ushort4*)(dst + u * 4) = o;
    }
  }
}

// ---------------------------------------------------------------------------
// Kernel 2: T = diag(1/colsum) * E^T @ contex -> T^T (bf16); also Q^T (bf16)
// Direct-global Et A-fragments (colsum folded in); only cx-transpose staged.
// grid 512 = B x 8 D-slices of 32; 256 threads (4 waves). LDS ~16KB.
// ---------------------------------------------------------------------------
__global__ __launch_bounds__(256) void k2_tmat(
    const float* __restrict__ cx, const float* __restrict__ qu,
    const unsigned short* __restrict__ Et,
    unsigned short* __restrict__ Qt, unsigned short* __restrict__ Tt)
{
  __shared__ unsigned short Bs2[32 * 72];
  __shared__ float Tl[64 * 37];
  __shared__ float red2[256];
  __shared__ float csinv[64];

  const int tid = threadIdx.x;
  const int b  = blockIdx.x >> 3;
  const int d0 = (blockIdx.x & 7) * 32;
  const int w = tid >> 6, lane = tid & 63, quad = lane >> 4, ln = lane & 15;

  // ---- transpose question slice -> Qt ----
  {
    const int j = tid >> 2, c = tid & 3;
    const float* srow = qu + ((size_t)(b * LQQ + j)) * DDD + d0 + c * 8;
    float4 v0 = *(const float4*)srow;
    float4 v1 = *(const float4*)(srow + 4);
    float* t = Tl + j * 37 + c * 8;
    t[0]=v0.x; t[1]=v0.y; t[2]=v0.z; t[3]=v0.w;
    t[4]=v1.x; t[5]=v1.y; t[6]=v1.z; t[7]=v1.w;
  }
  __syncthreads();
  {
    const int d = tid >> 3, cj = tid & 7;
    unsigned short* dst = Qt + ((size_t)(b * DDD + d0 + d)) * 64 + cj * 8;
    ushort4 o0 = { f2bf(Tl[(cj*8+0)*37+d]), f2bf(Tl[(cj*8+1)*37+d]),
                   f2bf(Tl[(cj*8+2)*37+d]), f2bf(Tl[(cj*8+3)*37+d]) };
    ushort4 o1 = { f2bf(Tl[(cj*8+4)*37+d]), f2bf(Tl[(cj*8+5)*37+d]),
                   f2bf(Tl[(cj*8+6)*37+d]), f2bf(Tl[(cj*8+7)*37+d]) };
    *(ushort4*)dst = o0;
    *(ushort4*)(dst + 4) = o1;
  }

  f32x4 acc[2];
  acc[0] = (f32x4){0.f, 0.f, 0.f, 0.f};
  acc[1] = (f32x4){0.f, 0.f, 0.f, 0.f};
  float csp = 0.f;
  const unsigned short* etrow = Et + ((size_t)(b * LQQ + w * 16 + ln)) * LCC;
  const int si = tid & 63, sc2 = tid >> 6;

  for (int kk = 0; kk < 8; ++kk) {
    __syncthreads();   // previous Bs2 reads done (also fences Qt-phase Tl reads at kk=0)
    // stage Bs2[d][i] = contex[k0+i][d0+d] (bf16 transposed)
    {
      const float* srow = cx + ((size_t)(b * LCC + kk * 64 + si)) * DDD + d0 + sc2 * 8;
      float4 v0 = *(const float4*)srow;
      float4 v1 = *(const float4*)(srow + 4);
      Bs2[(sc2*8+0)*72 + si] = f2bf(v0.x);
      Bs2[(sc2*8+1)*72 + si] = f2bf(v0.y);
      Bs2[(sc2*8+2)*72 + si] = f2bf(v0.z);
      Bs2[(sc2*8+3)*72 + si] = f2bf(v0.w);
      Bs2[(sc2*8+4)*72 + si] = f2bf(v1.x);
      Bs2[(sc2*8+5)*72 + si] = f2bf(v1.y);
      Bs2[(sc2*8+6)*72 + si] = f2bf(v1.z);
      Bs2[(sc2*8+7)*72 + si] = f2bf(v1.w);
    }
    // direct-global A fragments + colsum fold
    bf16x8 af0 = *(const bf16x8*)(etrow + kk * 64 + quad * 8);
    bf16x8 af1 = *(const bf16x8*)(etrow + kk * 64 + 32 + quad * 8);
#pragma unroll
    for (int e = 0; e < 8; ++e)
      csp += bf2f((unsigned short)af0[e]) + bf2f((unsigned short)af1[e]);
    __syncthreads();
#pragma unroll
    for (int tn = 0; tn < 2; ++tn) {
      bf16x8 bf0 = *(const bf16x8*)(Bs2 + (tn * 16 + ln) * 72 + quad * 8);
      bf16x8 bf1 = *(const bf16x8*)(Bs2 + (tn * 16 + ln) * 72 + 32 + quad * 8);
      acc[tn] = __builtin_amdgcn_mfma_f32_16x16x32_bf16(af0, bf0, acc[tn], 0, 0, 0);
      acc[tn] = __builtin_amdgcn_mfma_f32_16x16x32_bf16(af1, bf1, acc[tn], 0, 0, 0);
    }
  }

  __syncthreads();
  red2[(w * 16 + ln) * 4 + quad] = csp;
  __syncthreads();
  if (tid < 64)
    csinv[tid] = 1.0f / (red2[4*tid] + red2[4*tid+1] + red2[4*tid+2] + red2[4*tid+3]);
  __syncthreads();
  // park T (scaled) into Tl
#pragma unroll
  for (int tn = 0; tn < 2; ++tn)
#pragma unroll
    for (int r = 0; r < 4; ++r) {
      int j = w * 16 + quad * 4 + r;
      Tl[j * 37 + tn * 16 + ln] = acc[tn][r] * csinv[j];
    }
  __syncthreads();
  // write T^T (B, 256, 64) bf16
  {
    const int d = tid >> 3, cj = tid & 7;
    unsigned short* dst = Tt + ((size_t)(b * DDD + d0 + d)) * 64 + cj * 8;
    ushort4 o0 = { f2bf(Tl[(cj*8+0)*37+d]), f2bf(Tl[(cj*8+1)*37+d]),
                   f2bf(Tl[(cj*8+2)*37+d]), f2bf(Tl[(cj*8+3)*37+d]) };
    ushort4 o1 = { f2bf(Tl[(cj*8+4)*37+d]), f2bf(Tl[(cj*8+5)*37+d]),
                   f2bf(Tl[(cj*8+6)*37+d]), f2bf(Tl[(cj*8+7)*37+d]) };
    *(ushort4*)dst = o0;
    *(ushort4*)(dst + 4) = o1;
  }
}

// ---------------------------------------------------------------------------
// Kernel 3: [A|Bm] = diag(1/rowsum) * E @ [qu|T]; direct-global fragments,
// LDS only for the epilogue transpose. grid 1024 = B x 8 x 2 halves.
// ---------------------------------------------------------------------------
__global__ __launch_bounds__(256) void k3_out(
    const float* __restrict__ cx,
    const unsigned short* __restrict__ E,
    const unsigned short* __restrict__ Qt,
    const unsigned short* __restrict__ Tt,
    const float* __restrict__ rinv,
    float* __restrict__ out)
{
  __shared__ float Tr[16 * 260];
  __shared__ float ri_lds[64];

  const int tid = threadIdx.x;
  const int bid = blockIdx.x;
  const int b    = bid >> 4;
  const int it   = (bid >> 1) & 7;
  const int half = bid & 1;
  const int i0 = it * 64;
  const int w = tid >> 6, lane = tid & 63, quad = lane >> 4, ln = lane & 15;

  if (tid < 64) ri_lds[tid] = rinv[b * LCC + i0 + tid];

  const unsigned short* Bsrc = (half ? Tt : Qt) + (size_t)b * DDD * 64;
  const unsigned short* ebase = E + ((size_t)(b * LCC + i0)) * 64;

  f32x4 acc[4][4];
#pragma unroll
  for (int a = 0; a < 4; ++a)
#pragma unroll
    for (int c = 0; c < 4; ++c) acc[a][c] = (f32x4){0.f, 0.f, 0.f, 0.f};

#pragma unroll
  for (int ks = 0; ks < 2; ++ks) {
    bf16x8 af[4];
#pragma unroll
    for (int tm = 0; tm < 4; ++tm)
      af[tm] = *(const bf16x8*)(ebase + (tm * 16 + ln) * 64 + ks * 32 + quad * 8);
#pragma unroll
    for (int tn = 0; tn < 4; ++tn) {
      bf16x8 bf = *(const bf16x8*)(Bsrc + ((size_t)(w * 64 + tn * 16 + ln)) * 64 + ks * 32 + quad * 8);
#pragma unroll
      for (int tm = 0; tm < 4; ++tm)
        acc[tm][tn] = __builtin_amdgcn_mfma_f32_16x16x32_bf16(af[tm], bf, acc[tm][tn], 0, 0, 0);
    }
  }

  const float* cxb = cx + (size_t)b * LCC * DDD;
  float* ob = out + (size_t)b * LCC * 1024;
  const int row = tid >> 4;   // 0..15
  const int fq  = tid & 15;

  __syncthreads();   // ri_lds ready
#pragma unroll
  for (int tm = 0; tm < 4; ++tm) {
    // park 16 rows x 256 cols, rowsum-scaled, C/D-layout -> row-major
#pragma unroll
    for (int tn = 0; tn < 4; ++tn)
#pragma unroll
      for (int r = 0; r < 4; ++r) {
        int rloc = quad * 4 + r;
        Tr[rloc * 260 + w * 64 + tn * 16 + ln] = acc[tm][tn][r] * ri_lds[tm * 16 + rloc];
      }
    __syncthreads();
    const int i = i0 + tm * 16 + row;
#pragma unroll
    for (int u = 0; u < 4; ++u) {
      int c0 = (fq + u * 16) * 4;
      float4 v = *(const float4*)(Tr + row * 260 + c0);
      float4 c = *(const float4*)(cxb + (size_t)i * DDD + c0);
      float4 cv = { c.x * v.x, c.y * v.y, c.z * v.z, c.w * v.w };
      if (half == 0) {
        *(float4*)(ob + (size_t)i * 1024 + 256 + c0) = v;    // A
        *(float4*)(ob + (size_t)i * 1024 + 512 + c0) = cv;   // contex * A
      } else {
        *(float4*)(ob + (size_t)i * 1024 + c0)       = c;    // contex copy
        *(float4*)(ob + (size_t)i * 1024 + 768 + c0) = cv;   // contex * Bm
      }
    }
    __syncthreads();   // reads done before next park
  }
}

extern "C" void kernel_launch(void* const* d_in, const int* in_sizes, int n_in,
                              void* d_out, int out_size, void* d_ws, size_t ws_size,
                              hipStream_t stream) {
  const float* cx = (const float*)d_in[0];
  const float* qu = (const float*)d_in[1];
  const float* W  = (const float*)d_in[2];
  const float* Wb = (const float*)d_in[3];
  float* out = (float*)d_out;

  char* wsb = (char*)d_ws;
  unsigned short* E   = (unsigned short*)(wsb);                       // 4 MiB
  unsigned short* Et  = (unsigned short*)(wsb + (4ull << 20));        // 4 MiB
  unsigned short* Qt  = (unsigned short*)(wsb + (8ull << 20));        // 2 MiB
  unsigned short* Tt  = (unsigned short*)(wsb + (10ull << 20));       // 2 MiB
  float*          ri  = (float*)(wsb + (12ull << 20));                // 128 KiB

  k1_scores<<<dim3(512), dim3(256), 0, stream>>>(cx, qu, W, Wb, E, Et, ri);
  k2_tmat  <<<dim3(512), dim3(256), 0, stream>>>(cx, qu, Et, Qt, Tt);
  k3_out   <<<dim3(1024), dim3(256), 0, stream>>>(cx, E, Qt, Tt, ri, out);
}